// Round 1
// baseline (3448.583 us; speedup 1.0000x reference)
//
#include <hip/hip_runtime.h>
#include <hip/hip_bf16.h>

// GAT 2-layer forward for MI355X (gfx950).
// Layout of d_out (floats, return order):
//   [0, N*128)                       temp  = h2 flat
//   [N*128, N*128 + 4*N*32)          heads h2[:,i]  (4 slices of N*32)
//   [2*N*128, 2*N*128 + E*4)         e1
//   [.. + E)                         atten0
//   [.. + E)                         atten1
// Workspace (floats): feat(N*128) | h1(N*128) | eexp(E*4) | el(N*4) | er(N*4) | denom(N*4)

__device__ __forceinline__ void atomAddF(float* p, float v) {
    unsafeAtomicAdd(p, v);   // native global_atomic_add_f32 on gfx90a+
}

// ---------------- GEMM: Y[nrows,128] = X[nrows,K] @ W[K,128] ----------------
// 256 threads, tile 64 rows x 128 cols, Ktile=16. Thread = (tx 0..15, ty 0..15):
// rows ty*4..+3, cols {tx + 16j, j=0..7}. LDS reads conflict-free by layout.
__global__ __launch_bounds__(256) void gemm128(const float* __restrict__ X,
                                               const float* __restrict__ W,
                                               float* __restrict__ Y,
                                               int nrows, int K) {
    __shared__ float xs[16][68];    // xs[kk][r], pad 68 so ty*4 stride hits distinct banks
    __shared__ float ws[16][128];   // ws[kk][c]
    const int t  = threadIdx.x;
    const int tx = t & 15;
    const int ty = t >> 4;
    const int row0 = blockIdx.x * 64;
    float acc[4][8];
    #pragma unroll
    for (int i = 0; i < 4; ++i)
        #pragma unroll
        for (int j = 0; j < 8; ++j) acc[i][j] = 0.0f;

    for (int k0 = 0; k0 < K; k0 += 16) {
        // X tile: 64 rows x 16 k, float4 per thread
        {
            int r  = t >> 2;
            int c4 = (t & 3) << 2;
            int gr = row0 + r; if (gr >= nrows) gr = nrows - 1;
            const float4 v = *(const float4*)(X + (size_t)gr * K + k0 + c4);
            xs[c4 + 0][r] = v.x; xs[c4 + 1][r] = v.y;
            xs[c4 + 2][r] = v.z; xs[c4 + 3][r] = v.w;
        }
        // W tile: 16 k x 128 cols, two float4 per thread
        {
            int idx = t;
            #pragma unroll
            for (int p = 0; p < 2; ++p, idx += 256) {
                int r  = idx >> 5;
                int c4 = (idx & 31) << 2;
                *(float4*)&ws[r][c4] = *(const float4*)(W + (size_t)(k0 + r) * 128 + c4);
            }
        }
        __syncthreads();
        #pragma unroll
        for (int kk = 0; kk < 16; ++kk) {
            float4 a = *(const float4*)&xs[kk][ty * 4];   // 4 rows (16B aligned: 68*4=272=17*16)
            float b[8];
            #pragma unroll
            for (int j = 0; j < 8; ++j) b[j] = ws[kk][tx + 16 * j];
            const float av[4] = {a.x, a.y, a.z, a.w};
            #pragma unroll
            for (int i = 0; i < 4; ++i)
                #pragma unroll
                for (int j = 0; j < 8; ++j) acc[i][j] += av[i] * b[j];
        }
        __syncthreads();
    }
    #pragma unroll
    for (int i = 0; i < 4; ++i) {
        int gr = row0 + ty * 4 + i;
        if (gr < nrows) {
            #pragma unroll
            for (int j = 0; j < 8; ++j)
                Y[(size_t)gr * 128 + tx + 16 * j] = acc[i][j];
        }
    }
}

// ---------------- el/er: [N,4] head-wise dot with al/ar [4,32] ----------------
__global__ void eler_kernel(const float* __restrict__ feat,
                            const float* __restrict__ al,
                            const float* __restrict__ ar,
                            float* __restrict__ el, float* __restrict__ er, int n) {
    int i = blockIdx.x * blockDim.x + threadIdx.x;   // over N*4
    if (i >= n * 4) return;
    int node = i >> 2, h = i & 3;
    const float* f   = feat + (size_t)node * 128 + h * 32;
    const float* alh = al + h * 32;
    const float* arh = ar + h * 32;
    float sl = 0.0f, sr = 0.0f;
    #pragma unroll
    for (int d = 0; d < 32; d += 4) {
        float4 fv  = *(const float4*)(f + d);
        float4 alv = *(const float4*)(alh + d);
        float4 arv = *(const float4*)(arh + d);
        sl += fv.x * alv.x + fv.y * alv.y + fv.z * alv.z + fv.w * alv.w;
        sr += fv.x * arv.x + fv.y * arv.y + fv.z * arv.z + fv.w * arv.w;
    }
    el[i] = sl; er[i] = sr;
}

// ---------------- edge pass: scores, exp, denom atomics, score outputs --------
// No segment-max: |e| is bounded (<~10) so exp(e)/sum(exp(e)) == reference.
__global__ void edge_kernel(const int* __restrict__ srcs, const int* __restrict__ dsts,
                            const float* __restrict__ el, const float* __restrict__ er,
                            float* __restrict__ eexp, float* __restrict__ denom,
                            float* __restrict__ e_out,      // nullptr (layer0) or [E,4]
                            float* __restrict__ atten_out,  // [E]
                            int E) {
    int e = blockIdx.x * blockDim.x + threadIdx.x;
    if (e >= E) return;
    int s = srcs[e], d = dsts[e];
    float4 elv = *(const float4*)(el + 4 * (size_t)s);
    float4 erv = *(const float4*)(er + 4 * (size_t)d);
    float v[4] = {elv.x + erv.x, elv.y + erv.y, elv.z + erv.z, elv.w + erv.w};
    float ex[4];
    float sum = 0.0f;
    #pragma unroll
    for (int h = 0; h < 4; ++h) {
        float lr = v[h] > 0.0f ? v[h] : 0.2f * v[h];
        v[h] = lr;
        sum += lr;
        ex[h] = __expf(lr);
        atomAddF(&denom[4 * (size_t)d + h], ex[h]);
    }
    *(float4*)(eexp + 4 * (size_t)e) = make_float4(ex[0], ex[1], ex[2], ex[3]);
    if (e_out) *(float4*)(e_out + 4 * (size_t)e) = make_float4(v[0], v[1], v[2], v[3]);
    atten_out[e] = sum * 0.25f;
}

// ---------------- message aggregation: rst[dst] += feat[src] * a --------------
// 32 threads per edge, float4 each (128 cols). Atomic scatter-add.
__global__ __launch_bounds__(256) void msg_kernel(const int* __restrict__ srcs,
                                                  const int* __restrict__ dsts,
                                                  const float* __restrict__ feat,
                                                  const float* __restrict__ eexp,
                                                  const float* __restrict__ denom,
                                                  float* __restrict__ rst, int E) {
    int gid = blockIdx.x * blockDim.x + threadIdx.x;
    int e = gid >> 5;
    if (e >= E) return;
    int sub = gid & 31;           // cols sub*4 .. sub*4+3
    int h = sub >> 3;
    int s = srcs[e], d = dsts[e];
    float a = eexp[4 * (size_t)e + h] / denom[4 * (size_t)d + h];
    float4 f = *(const float4*)(feat + 128 * (size_t)s + sub * 4);
    float* r = rst + 128 * (size_t)d + sub * 4;
    atomAddF(r + 0, f.x * a);
    atomAddF(r + 1, f.y * a);
    atomAddF(r + 2, f.z * a);
    atomAddF(r + 3, f.w * a);
}

// ---------------- elu in place (float4) ----------------
__global__ void elu4_kernel(float4* __restrict__ buf, int n4) {
    int i = blockIdx.x * blockDim.x + threadIdx.x;
    if (i >= n4) return;
    float4 v = buf[i];
    v.x = v.x > 0.0f ? v.x : __expf(v.x) - 1.0f;
    v.y = v.y > 0.0f ? v.y : __expf(v.y) - 1.0f;
    v.z = v.z > 0.0f ? v.z : __expf(v.z) - 1.0f;
    v.w = v.w > 0.0f ? v.w : __expf(v.w) - 1.0f;
    buf[i] = v;
}

// ---------------- layer-1 epilogue: residual + elu, write temp + head slices --
__global__ void final_kernel(const float* __restrict__ h1, float* __restrict__ out,
                             int n) {
    int i = blockIdx.x * blockDim.x + threadIdx.x;   // over N*128
    if (i >= n * 128) return;
    float v = out[i] + h1[i];                         // rst1 + residual
    v = v > 0.0f ? v : __expf(v) - 1.0f;              // elu
    out[i] = v;                                       // temp
    int node = i >> 7, c = i & 127;
    int h = c >> 5, dd = c & 31;
    size_t head_base = (size_t)n * 128;
    out[head_base + (size_t)h * n * 32 + (size_t)node * 32 + dd] = v;
}

extern "C" void kernel_launch(void* const* d_in, const int* in_sizes, int n_in,
                              void* d_out, int out_size, void* d_ws, size_t ws_size,
                              hipStream_t stream) {
    const float* x   = (const float*)d_in[0];
    const int*   ei  = (const int*)d_in[1];
    const float* W0  = (const float*)d_in[2];
    const float* al0 = (const float*)d_in[3];
    const float* ar0 = (const float*)d_in[4];
    const float* W1  = (const float*)d_in[5];
    const float* al1 = (const float*)d_in[6];
    const float* ar1 = (const float*)d_in[7];

    const int N = in_sizes[0] / 256;     // 100000
    const int E = in_sizes[1] / 2;       // 800000
    const size_t NF = (size_t)N * 128;   // 12.8M

    const int* srcs = ei;
    const int* dsts = ei + E;

    float* out = (float*)d_out;
    float* ws  = (float*)d_ws;
    float* feat  = ws;                       // N*128
    float* h1    = ws + NF;                  // N*128
    float* eexp  = ws + 2 * NF;              // E*4
    float* el    = ws + 2 * NF + (size_t)E * 4;            // N*4
    float* er    = el + (size_t)N * 4;                      // N*4
    float* denom = er + (size_t)N * 4;                      // N*4

    // d_out sub-regions
    float* e1_out     = out + 2 * NF;                       // E*4
    float* atten0_out = e1_out + (size_t)E * 4;             // E
    float* atten1_out = atten0_out + E;                     // E

    // zero-init accumulators (d_ws/d_out are poisoned 0xAA before every call)
    hipMemsetAsync(h1, 0, NF * sizeof(float), stream);                 // rst0
    hipMemsetAsync(denom, 0, (size_t)N * 4 * sizeof(float), stream);
    hipMemsetAsync(out, 0, NF * sizeof(float), stream);                // rst1

    const int gemm_blocks = (N + 63) / 64;

    // ---- layer 0 ----
    gemm128<<<gemm_blocks, 256, 0, stream>>>(x, W0, feat, N, 256);
    eler_kernel<<<(N * 4 + 255) / 256, 256, 0, stream>>>(feat, al0, ar0, el, er, N);
    edge_kernel<<<(E + 255) / 256, 256, 0, stream>>>(srcs, dsts, el, er, eexp, denom,
                                                     nullptr, atten0_out, E);
    msg_kernel<<<(E * 32 + 255) / 256, 256, 0, stream>>>(srcs, dsts, feat, eexp, denom,
                                                         h1, E);
    elu4_kernel<<<(int)((NF / 4 + 255) / 256), 256, 0, stream>>>((float4*)h1, (int)(NF / 4));

    // ---- layer 1 ----
    gemm128<<<gemm_blocks, 256, 0, stream>>>(h1, W1, feat, N, 128);
    eler_kernel<<<(N * 4 + 255) / 256, 256, 0, stream>>>(feat, al1, ar1, el, er, N);
    hipMemsetAsync(denom, 0, (size_t)N * 4 * sizeof(float), stream);
    edge_kernel<<<(E + 255) / 256, 256, 0, stream>>>(srcs, dsts, el, er, eexp, denom,
                                                     e1_out, atten1_out, E);
    msg_kernel<<<(E * 32 + 255) / 256, 256, 0, stream>>>(srcs, dsts, feat, eexp, denom,
                                                         out, E);
    final_kernel<<<(N * 128 + 255) / 256, 256, 0, stream>>>(h1, out, N);
}

// Round 2
// 888.184 us; speedup vs baseline: 3.8827x; 3.8827x over previous
//
#include <hip/hip_runtime.h>
#include <hip/hip_bf16.h>

// GAT 2-layer forward for MI355X (gfx950). Round 2: CSR gather, no float atomics.
//
// d_out (floats, return order):
//   [0, N*128)            temp = h2 flat
//   [N*128, N*128+4*N*32) heads h2[:,i]
//   [2*N*128, +E*4)       e1
//   [+E]                  atten0
//   [+E]                  atten1
//
// Workspace: feat(N*128) | h1(N*128) | eexp(E*4) | el(N*4) | er(N*4) |
//            ints: deg(N) row_off(N) cursor(N) eid(E) bsums(256)

// ---------------- GEMM: Y[nrows,128] = X[nrows,K] @ W[K,128] ----------------
__global__ __launch_bounds__(256) void gemm128(const float* __restrict__ X,
                                               const float* __restrict__ W,
                                               float* __restrict__ Y,
                                               int nrows, int K) {
    __shared__ float xs[16][68];
    __shared__ float ws[16][128];
    const int t  = threadIdx.x;
    const int tx = t & 15;
    const int ty = t >> 4;
    const int row0 = blockIdx.x * 64;
    float acc[4][8];
    #pragma unroll
    for (int i = 0; i < 4; ++i)
        #pragma unroll
        for (int j = 0; j < 8; ++j) acc[i][j] = 0.0f;

    for (int k0 = 0; k0 < K; k0 += 16) {
        {
            int r  = t >> 2;
            int c4 = (t & 3) << 2;
            int gr = row0 + r; if (gr >= nrows) gr = nrows - 1;
            const float4 v = *(const float4*)(X + (size_t)gr * K + k0 + c4);
            xs[c4 + 0][r] = v.x; xs[c4 + 1][r] = v.y;
            xs[c4 + 2][r] = v.z; xs[c4 + 3][r] = v.w;
        }
        {
            int idx = t;
            #pragma unroll
            for (int p = 0; p < 2; ++p, idx += 256) {
                int r  = idx >> 5;
                int c4 = (idx & 31) << 2;
                *(float4*)&ws[r][c4] = *(const float4*)(W + (size_t)(k0 + r) * 128 + c4);
            }
        }
        __syncthreads();
        #pragma unroll
        for (int kk = 0; kk < 16; ++kk) {
            float4 a = *(const float4*)&xs[kk][ty * 4];
            float b[8];
            #pragma unroll
            for (int j = 0; j < 8; ++j) b[j] = ws[kk][tx + 16 * j];
            const float av[4] = {a.x, a.y, a.z, a.w};
            #pragma unroll
            for (int i = 0; i < 4; ++i)
                #pragma unroll
                for (int j = 0; j < 8; ++j) acc[i][j] += av[i] * b[j];
        }
        __syncthreads();
    }
    #pragma unroll
    for (int i = 0; i < 4; ++i) {
        int gr = row0 + ty * 4 + i;
        if (gr < nrows) {
            #pragma unroll
            for (int j = 0; j < 8; ++j)
                Y[(size_t)gr * 128 + tx + 16 * j] = acc[i][j];
        }
    }
}

// ---------------- el/er: [N,4] head-wise dot with al/ar [4,32] ----------------
__global__ void eler_kernel(const float* __restrict__ feat,
                            const float* __restrict__ al,
                            const float* __restrict__ ar,
                            float* __restrict__ el, float* __restrict__ er, int n) {
    int i = blockIdx.x * blockDim.x + threadIdx.x;
    if (i >= n * 4) return;
    int node = i >> 2, h = i & 3;
    const float* f   = feat + (size_t)node * 128 + h * 32;
    const float* alh = al + h * 32;
    const float* arh = ar + h * 32;
    float sl = 0.0f, sr = 0.0f;
    #pragma unroll
    for (int d = 0; d < 32; d += 4) {
        float4 fv  = *(const float4*)(f + d);
        float4 alv = *(const float4*)(alh + d);
        float4 arv = *(const float4*)(arh + d);
        sl += fv.x * alv.x + fv.y * alv.y + fv.z * alv.z + fv.w * alv.w;
        sr += fv.x * arv.x + fv.y * arv.y + fv.z * arv.z + fv.w * arv.w;
    }
    el[i] = sl; er[i] = sr;
}

// ---------------- CSR build ----------------
__global__ void count_deg(const int* __restrict__ dsts, int* __restrict__ deg, int E) {
    int e = blockIdx.x * blockDim.x + threadIdx.x;
    if (e < E) atomicAdd(&deg[dsts[e]], 1);
}

// Block-level exclusive scan, tile = 1024 (256 thr x 4). Writes per-element
// exclusive-within-block into excl[], block totals into bsums[].
__global__ __launch_bounds__(256) void scan_block(const int* __restrict__ deg,
                                                  int* __restrict__ excl,
                                                  int* __restrict__ bsums, int n) {
    __shared__ int wsums[4];
    int t = threadIdx.x;
    int base = blockIdx.x * 1024;
    int idx = base + t * 4;
    int v[4];
    #pragma unroll
    for (int i = 0; i < 4; ++i) v[i] = (idx + i < n) ? deg[idx + i] : 0;
    int tsum = v[0] + v[1] + v[2] + v[3];
    int lane = t & 63, wid = t >> 6;
    int incl = tsum;
    #pragma unroll
    for (int off = 1; off < 64; off <<= 1) {
        int u = __shfl_up(incl, off, 64);
        if (lane >= off) incl += u;
    }
    if (lane == 63) wsums[wid] = incl;
    __syncthreads();
    if (t == 0) {
        int s = 0;
        #pragma unroll
        for (int w = 0; w < 4; ++w) { int x = wsums[w]; wsums[w] = s; s += x; }
    }
    __syncthreads();
    int ex = incl - tsum + wsums[wid];   // exclusive prefix of this thread's first item
    int run = ex;
    #pragma unroll
    for (int i = 0; i < 4; ++i) { if (idx + i < n) excl[idx + i] = run; run += v[i]; }
    if (t == 255) bsums[blockIdx.x] = ex + tsum;   // block total
}

// Single-block exclusive scan of nb (<=256) block sums, in place.
__global__ __launch_bounds__(256) void scan_sums(int* __restrict__ bs, int nb) {
    __shared__ int wsums[4];
    int t = threadIdx.x;
    int v = (t < nb) ? bs[t] : 0;
    int lane = t & 63, wid = t >> 6;
    int incl = v;
    #pragma unroll
    for (int off = 1; off < 64; off <<= 1) {
        int u = __shfl_up(incl, off, 64);
        if (lane >= off) incl += u;
    }
    if (lane == 63) wsums[wid] = incl;
    __syncthreads();
    if (t == 0) {
        int s = 0;
        #pragma unroll
        for (int w = 0; w < 4; ++w) { int x = wsums[w]; wsums[w] = s; s += x; }
    }
    __syncthreads();
    if (t < nb) bs[t] = incl - v + wsums[wid];
}

__global__ void scan_finalize(int* __restrict__ row_off, const int* __restrict__ bsums,
                              int* __restrict__ cursor, int n) {
    int i = blockIdx.x * blockDim.x + threadIdx.x;
    if (i < n) {
        int v = row_off[i] + bsums[i >> 10];
        row_off[i] = v;
        cursor[i]  = v;
    }
}

__global__ void fill_csr(const int* __restrict__ dsts, int* __restrict__ cursor,
                         int* __restrict__ eid, int E) {
    int e = blockIdx.x * blockDim.x + threadIdx.x;
    if (e < E) {
        int p = atomicAdd(&cursor[dsts[e]], 1);
        eid[p] = e;
    }
}

// ---------------- edge pass: scores, exp, score outputs (no atomics) --------
__global__ void edge_kernel(const int* __restrict__ srcs, const int* __restrict__ dsts,
                            const float* __restrict__ el, const float* __restrict__ er,
                            float* __restrict__ eexp,
                            float* __restrict__ e_out,      // nullptr (layer0) or [E,4]
                            float* __restrict__ atten_out,  // [E]
                            int E) {
    int e = blockIdx.x * blockDim.x + threadIdx.x;
    if (e >= E) return;
    int s = srcs[e], d = dsts[e];
    float4 elv = *(const float4*)(el + 4 * (size_t)s);
    float4 erv = *(const float4*)(er + 4 * (size_t)d);
    float v[4] = {elv.x + erv.x, elv.y + erv.y, elv.z + erv.z, elv.w + erv.w};
    float ex[4];
    float sum = 0.0f;
    #pragma unroll
    for (int h = 0; h < 4; ++h) {
        float lr = v[h] > 0.0f ? v[h] : 0.2f * v[h];
        v[h] = lr;
        sum += lr;
        ex[h] = __expf(lr);
    }
    *(float4*)(eexp + 4 * (size_t)e) = make_float4(ex[0], ex[1], ex[2], ex[3]);
    if (e_out) *(float4*)(e_out + 4 * (size_t)e) = make_float4(v[0], v[1], v[2], v[3]);
    atten_out[e] = sum * 0.25f;
}

// ---------------- gather aggregation: one wave per dst node -----------------
// lane l: cols l*2, l*2+1; head h = l>>4. denom in-register, fused epilogue.
template <int LAYER>
__global__ __launch_bounds__(256) void aggregate(const int* __restrict__ row_off,
                                                 const int* __restrict__ deg,
                                                 const int* __restrict__ eid,
                                                 const int* __restrict__ srcs,
                                                 const float* __restrict__ eexp,
                                                 const float* __restrict__ feat,
                                                 const float* __restrict__ resid, // h1 for layer1
                                                 float* __restrict__ out0,        // h1 or temp
                                                 float* __restrict__ heads,       // out+NF (layer1)
                                                 int N) {
    int wave = (blockIdx.x * 256 + threadIdx.x) >> 6;
    if (wave >= N) return;
    int lane = threadIdx.x & 63;
    int n = wave;
    int start = row_off[n];
    int dc    = deg[n];
    int h  = lane >> 4;
    int c0 = lane * 2;

    float dh = 0.0f;
    for (int i = 0; i < dc; ++i) {
        int e = eid[start + i];
        dh += eexp[4 * (size_t)e + h];
    }
    float inv = (dc > 0) ? 1.0f / dh : 0.0f;

    float2 acc = make_float2(0.0f, 0.0f);
    for (int i = 0; i < dc; ++i) {
        int e = eid[start + i];
        float a = eexp[4 * (size_t)e + h] * inv;
        int s = srcs[e];
        float2 f = *(const float2*)(feat + 128 * (size_t)s + c0);
        acc.x += f.x * a;
        acc.y += f.y * a;
    }
    size_t o = 128 * (size_t)n + c0;
    if (LAYER == 1) { acc.x += resid[o]; acc.y += resid[o + 1]; }
    acc.x = acc.x > 0.0f ? acc.x : __expf(acc.x) - 1.0f;
    acc.y = acc.y > 0.0f ? acc.y : __expf(acc.y) - 1.0f;
    *(float2*)(out0 + o) = acc;
    if (LAYER == 1) {
        int dd = c0 & 31;
        *(float2*)(heads + (size_t)h * N * 32 + (size_t)n * 32 + dd) = acc;
    }
}

extern "C" void kernel_launch(void* const* d_in, const int* in_sizes, int n_in,
                              void* d_out, int out_size, void* d_ws, size_t ws_size,
                              hipStream_t stream) {
    const float* x   = (const float*)d_in[0];
    const int*   ei  = (const int*)d_in[1];
    const float* W0  = (const float*)d_in[2];
    const float* al0 = (const float*)d_in[3];
    const float* ar0 = (const float*)d_in[4];
    const float* W1  = (const float*)d_in[5];
    const float* al1 = (const float*)d_in[6];
    const float* ar1 = (const float*)d_in[7];

    const int N = in_sizes[0] / 256;     // 100000
    const int E = in_sizes[1] / 2;       // 800000
    const size_t NF = (size_t)N * 128;

    const int* srcs = ei;
    const int* dsts = ei + E;

    float* out = (float*)d_out;
    float* ws  = (float*)d_ws;
    float* feat = ws;                                    // N*128
    float* h1   = ws + NF;                               // N*128
    float* eexp = ws + 2 * NF;                           // E*4
    float* el   = eexp + (size_t)E * 4;                  // N*4
    float* er   = el + (size_t)N * 4;                    // N*4
    int*   ints    = (int*)(er + (size_t)N * 4);
    int*   deg     = ints;                               // N
    int*   row_off = deg + N;                            // N
    int*   cursor  = row_off + N;                        // N
    int*   eid     = cursor + N;                         // E
    int*   bsums   = eid + E;                            // <=256

    // d_out sub-regions
    float* heads      = out + NF;                        // 4*N*32
    float* e1_out     = out + 2 * NF;                    // E*4
    float* atten0_out = e1_out + (size_t)E * 4;          // E
    float* atten1_out = atten0_out + E;                  // E

    // ---- CSR build (int atomics only) ----
    hipMemsetAsync(deg, 0, (size_t)N * sizeof(int), stream);
    count_deg<<<(E + 255) / 256, 256, 0, stream>>>(dsts, deg, E);
    int nb = (N + 1023) / 1024;
    scan_block<<<nb, 256, 0, stream>>>(deg, row_off, bsums, N);
    scan_sums<<<1, 256, 0, stream>>>(bsums, nb);
    scan_finalize<<<(N + 255) / 256, 256, 0, stream>>>(row_off, bsums, cursor, N);
    fill_csr<<<(E + 255) / 256, 256, 0, stream>>>(dsts, cursor, eid, E);

    const int gemm_blocks = (N + 63) / 64;
    const int agg_blocks  = (N + 3) / 4;   // 1 wave/node, 4 waves/block

    // ---- layer 0 ----
    gemm128<<<gemm_blocks, 256, 0, stream>>>(x, W0, feat, N, 256);
    eler_kernel<<<(N * 4 + 255) / 256, 256, 0, stream>>>(feat, al0, ar0, el, er, N);
    edge_kernel<<<(E + 255) / 256, 256, 0, stream>>>(srcs, dsts, el, er, eexp,
                                                     nullptr, atten0_out, E);
    aggregate<0><<<agg_blocks, 256, 0, stream>>>(row_off, deg, eid, srcs, eexp, feat,
                                                 nullptr, h1, nullptr, N);

    // ---- layer 1 ----
    gemm128<<<gemm_blocks, 256, 0, stream>>>(h1, W1, feat, N, 128);
    eler_kernel<<<(N * 4 + 255) / 256, 256, 0, stream>>>(feat, al1, ar1, el, er, N);
    edge_kernel<<<(E + 255) / 256, 256, 0, stream>>>(srcs, dsts, el, er, eexp,
                                                     e1_out, atten1_out, E);
    aggregate<1><<<agg_blocks, 256, 0, stream>>>(row_off, deg, eid, srcs, eexp, feat,
                                                 h1, out, heads, N);
}

// Round 3
// 655.789 us; speedup vs baseline: 5.2587x; 1.3544x over previous
//
#include <hip/hip_runtime.h>
#include <hip/hip_bf16.h>

// GAT 2-layer forward for MI355X (gfx950). Round 3: single-pass CSR gather,
// de-indirected (csr_src + CSR-ordered exp weights), shfl-broadcast srcs for MLP.
//
// d_out (floats, return order):
//   [0, N*128)            temp = h2 flat
//   [N*128, N*128+4*N*32) heads h2[:,i]
//   [2*N*128, +E*4)       e1
//   [+E]                  atten0
//   [+E]                  atten1
//
// Workspace: feat(N*128) | h1(N*128) | exw(E*4, CSR order) | el(N*4) | er(N*4) |
//            ints: deg(N) row_off(N) cursor(N) csr_src(E) pos(E) bsums(256)

// ---------------- GEMM: Y[nrows,128] = X[nrows,K] @ W[K,128] ----------------
__global__ __launch_bounds__(256) void gemm128(const float* __restrict__ X,
                                               const float* __restrict__ W,
                                               float* __restrict__ Y,
                                               int nrows, int K) {
    __shared__ float xs[16][68];
    __shared__ float ws[16][128];
    const int t  = threadIdx.x;
    const int tx = t & 15;
    const int ty = t >> 4;
    const int row0 = blockIdx.x * 64;
    float acc[4][8];
    #pragma unroll
    for (int i = 0; i < 4; ++i)
        #pragma unroll
        for (int j = 0; j < 8; ++j) acc[i][j] = 0.0f;

    for (int k0 = 0; k0 < K; k0 += 16) {
        {
            int r  = t >> 2;
            int c4 = (t & 3) << 2;
            int gr = row0 + r; if (gr >= nrows) gr = nrows - 1;
            const float4 v = *(const float4*)(X + (size_t)gr * K + k0 + c4);
            xs[c4 + 0][r] = v.x; xs[c4 + 1][r] = v.y;
            xs[c4 + 2][r] = v.z; xs[c4 + 3][r] = v.w;
        }
        {
            int idx = t;
            #pragma unroll
            for (int p = 0; p < 2; ++p, idx += 256) {
                int r  = idx >> 5;
                int c4 = (idx & 31) << 2;
                *(float4*)&ws[r][c4] = *(const float4*)(W + (size_t)(k0 + r) * 128 + c4);
            }
        }
        __syncthreads();
        #pragma unroll
        for (int kk = 0; kk < 16; ++kk) {
            float4 a = *(const float4*)&xs[kk][ty * 4];
            float b[8];
            #pragma unroll
            for (int j = 0; j < 8; ++j) b[j] = ws[kk][tx + 16 * j];
            const float av[4] = {a.x, a.y, a.z, a.w};
            #pragma unroll
            for (int i = 0; i < 4; ++i)
                #pragma unroll
                for (int j = 0; j < 8; ++j) acc[i][j] += av[i] * b[j];
        }
        __syncthreads();
    }
    #pragma unroll
    for (int i = 0; i < 4; ++i) {
        int gr = row0 + ty * 4 + i;
        if (gr < nrows) {
            #pragma unroll
            for (int j = 0; j < 8; ++j)
                Y[(size_t)gr * 128 + tx + 16 * j] = acc[i][j];
        }
    }
}

// ---------------- el/er: [N,4] head-wise dot with al/ar [4,32] ----------------
__global__ void eler_kernel(const float* __restrict__ feat,
                            const float* __restrict__ al,
                            const float* __restrict__ ar,
                            float* __restrict__ el, float* __restrict__ er, int n) {
    int i = blockIdx.x * blockDim.x + threadIdx.x;
    if (i >= n * 4) return;
    int node = i >> 2, h = i & 3;
    const float* f   = feat + (size_t)node * 128 + h * 32;
    const float* alh = al + h * 32;
    const float* arh = ar + h * 32;
    float sl = 0.0f, sr = 0.0f;
    #pragma unroll
    for (int d = 0; d < 32; d += 4) {
        float4 fv  = *(const float4*)(f + d);
        float4 alv = *(const float4*)(alh + d);
        float4 arv = *(const float4*)(arh + d);
        sl += fv.x * alv.x + fv.y * alv.y + fv.z * alv.z + fv.w * alv.w;
        sr += fv.x * arv.x + fv.y * arv.y + fv.z * arv.z + fv.w * arv.w;
    }
    el[i] = sl; er[i] = sr;
}

// ---------------- CSR build ----------------
__global__ void count_deg(const int* __restrict__ dsts, int* __restrict__ deg, int E) {
    int e = blockIdx.x * blockDim.x + threadIdx.x;
    if (e < E) atomicAdd(&deg[dsts[e]], 1);
}

__global__ __launch_bounds__(256) void scan_block(const int* __restrict__ deg,
                                                  int* __restrict__ excl,
                                                  int* __restrict__ bsums, int n) {
    __shared__ int wsums[4];
    int t = threadIdx.x;
    int base = blockIdx.x * 1024;
    int idx = base + t * 4;
    int v[4];
    #pragma unroll
    for (int i = 0; i < 4; ++i) v[i] = (idx + i < n) ? deg[idx + i] : 0;
    int tsum = v[0] + v[1] + v[2] + v[3];
    int lane = t & 63, wid = t >> 6;
    int incl = tsum;
    #pragma unroll
    for (int off = 1; off < 64; off <<= 1) {
        int u = __shfl_up(incl, off, 64);
        if (lane >= off) incl += u;
    }
    if (lane == 63) wsums[wid] = incl;
    __syncthreads();
    if (t == 0) {
        int s = 0;
        #pragma unroll
        for (int w = 0; w < 4; ++w) { int x = wsums[w]; wsums[w] = s; s += x; }
    }
    __syncthreads();
    int ex = incl - tsum + wsums[wid];
    int run = ex;
    #pragma unroll
    for (int i = 0; i < 4; ++i) { if (idx + i < n) excl[idx + i] = run; run += v[i]; }
    if (t == 255) bsums[blockIdx.x] = ex + tsum;
}

__global__ __launch_bounds__(256) void scan_sums(int* __restrict__ bs, int nb) {
    __shared__ int wsums[4];
    int t = threadIdx.x;
    int v = (t < nb) ? bs[t] : 0;
    int lane = t & 63, wid = t >> 6;
    int incl = v;
    #pragma unroll
    for (int off = 1; off < 64; off <<= 1) {
        int u = __shfl_up(incl, off, 64);
        if (lane >= off) incl += u;
    }
    if (lane == 63) wsums[wid] = incl;
    __syncthreads();
    if (t == 0) {
        int s = 0;
        #pragma unroll
        for (int w = 0; w < 4; ++w) { int x = wsums[w]; wsums[w] = s; s += x; }
    }
    __syncthreads();
    if (t < nb) bs[t] = incl - v + wsums[wid];
}

__global__ void scan_finalize(int* __restrict__ row_off, const int* __restrict__ bsums,
                              int* __restrict__ cursor, int n) {
    int i = blockIdx.x * blockDim.x + threadIdx.x;
    if (i < n) {
        int v = row_off[i] + bsums[i >> 10];
        row_off[i] = v;
        cursor[i]  = v;
    }
}

__global__ void fill_csr(const int* __restrict__ dsts, const int* __restrict__ srcs,
                         int* __restrict__ cursor, int* __restrict__ csr_src,
                         int* __restrict__ pos, int E) {
    int e = blockIdx.x * blockDim.x + threadIdx.x;
    if (e < E) {
        int p = atomicAdd(&cursor[dsts[e]], 1);
        csr_src[p] = srcs[e];
        pos[e] = p;
    }
}

// ---------------- edge pass: scores, exp (scattered to CSR order) -----------
__global__ void edge_kernel(const int* __restrict__ srcs, const int* __restrict__ dsts,
                            const int* __restrict__ pos,
                            const float* __restrict__ el, const float* __restrict__ er,
                            float* __restrict__ exw,        // [E,4] CSR order
                            float* __restrict__ e_out,      // nullptr (layer0) or [E,4]
                            float* __restrict__ atten_out,  // [E]
                            int E) {
    int e = blockIdx.x * blockDim.x + threadIdx.x;
    if (e >= E) return;
    int s = srcs[e], d = dsts[e];
    float4 elv = *(const float4*)(el + 4 * (size_t)s);
    float4 erv = *(const float4*)(er + 4 * (size_t)d);
    float v[4] = {elv.x + erv.x, elv.y + erv.y, elv.z + erv.z, elv.w + erv.w};
    float ex[4];
    float sum = 0.0f;
    #pragma unroll
    for (int h = 0; h < 4; ++h) {
        float lr = v[h] > 0.0f ? v[h] : 0.2f * v[h];
        v[h] = lr;
        sum += lr;
        ex[h] = __expf(lr);
    }
    int p = pos[e];
    *(float4*)(exw + 4 * (size_t)p) = make_float4(ex[0], ex[1], ex[2], ex[3]);
    if (e_out) *(float4*)(e_out + 4 * (size_t)e) = make_float4(v[0], v[1], v[2], v[3]);
    atten_out[e] = sum * 0.25f;
}

// ---------------- gather aggregation: one wave per dst node -----------------
// Single pass: acc = sum(exp * feat[src]); dh = sum(exp); result = acc/dh.
// srcs preloaded one-per-lane, broadcast via __shfl (v_readlane) so all feat
// row addresses are known up front -> deep MLP.
template <int LAYER>
__global__ __launch_bounds__(256) void aggregate(const int* __restrict__ row_off,
                                                 const int* __restrict__ deg,
                                                 const int* __restrict__ csr_src,
                                                 const float* __restrict__ exw,
                                                 const float* __restrict__ feat,
                                                 const float* __restrict__ resid,
                                                 float* __restrict__ out0,
                                                 float* __restrict__ heads,
                                                 int N) {
    int wave = (blockIdx.x * 256 + threadIdx.x) >> 6;
    if (wave >= N) return;
    int lane = threadIdx.x & 63;
    int start = row_off[wave];
    int dc    = deg[wave];
    int h  = lane >> 4;
    int c0 = lane * 2;

    float dh = 0.0f;
    float2 acc = make_float2(0.0f, 0.0f);

    for (int cs = 0; cs < dc; cs += 64) {
        int act = dc - cs; if (act > 64) act = 64;
        int sl = (lane < act) ? csr_src[start + cs + lane] : 0;
        const float* wp = exw + 4 * (size_t)(start + cs) + h;
        int i = 0;
        for (; i + 4 <= act; i += 4) {
            int s0 = __shfl(sl, i);
            int s1 = __shfl(sl, i + 1);
            int s2 = __shfl(sl, i + 2);
            int s3 = __shfl(sl, i + 3);
            float w0 = wp[4 * i];
            float w1 = wp[4 * (i + 1)];
            float w2 = wp[4 * (i + 2)];
            float w3 = wp[4 * (i + 3)];
            float2 f0 = *(const float2*)(feat + 128 * (size_t)s0 + c0);
            float2 f1 = *(const float2*)(feat + 128 * (size_t)s1 + c0);
            float2 f2 = *(const float2*)(feat + 128 * (size_t)s2 + c0);
            float2 f3 = *(const float2*)(feat + 128 * (size_t)s3 + c0);
            acc.x += w0 * f0.x; acc.y += w0 * f0.y;
            acc.x += w1 * f1.x; acc.y += w1 * f1.y;
            acc.x += w2 * f2.x; acc.y += w2 * f2.y;
            acc.x += w3 * f3.x; acc.y += w3 * f3.y;
            dh += w0 + w1 + w2 + w3;
        }
        for (; i < act; ++i) {
            int s = __shfl(sl, i);
            float w = wp[4 * i];
            float2 f = *(const float2*)(feat + 128 * (size_t)s + c0);
            acc.x += w * f.x; acc.y += w * f.y;
            dh += w;
        }
    }

    float inv = (dc > 0) ? 1.0f / dh : 0.0f;
    acc.x *= inv; acc.y *= inv;
    size_t o = 128 * (size_t)wave + c0;
    if (LAYER == 1) { acc.x += resid[o]; acc.y += resid[o + 1]; }
    acc.x = acc.x > 0.0f ? acc.x : __expf(acc.x) - 1.0f;
    acc.y = acc.y > 0.0f ? acc.y : __expf(acc.y) - 1.0f;
    *(float2*)(out0 + o) = acc;
    if (LAYER == 1) {
        *(float2*)(heads + (size_t)h * N * 32 + (size_t)wave * 32 + (c0 & 31)) = acc;
    }
}

extern "C" void kernel_launch(void* const* d_in, const int* in_sizes, int n_in,
                              void* d_out, int out_size, void* d_ws, size_t ws_size,
                              hipStream_t stream) {
    const float* x   = (const float*)d_in[0];
    const int*   ei  = (const int*)d_in[1];
    const float* W0  = (const float*)d_in[2];
    const float* al0 = (const float*)d_in[3];
    const float* ar0 = (const float*)d_in[4];
    const float* W1  = (const float*)d_in[5];
    const float* al1 = (const float*)d_in[6];
    const float* ar1 = (const float*)d_in[7];

    const int N = in_sizes[0] / 256;     // 100000
    const int E = in_sizes[1] / 2;       // 800000
    const size_t NF = (size_t)N * 128;

    const int* srcs = ei;
    const int* dsts = ei + E;

    float* out = (float*)d_out;
    float* ws  = (float*)d_ws;
    float* feat = ws;                                    // N*128
    float* h1   = ws + NF;                               // N*128
    float* exw  = ws + 2 * NF;                           // E*4 (CSR order)
    float* el   = exw + (size_t)E * 4;                   // N*4
    float* er   = el + (size_t)N * 4;                    // N*4
    int*   ints    = (int*)(er + (size_t)N * 4);
    int*   deg     = ints;                               // N
    int*   row_off = deg + N;                            // N
    int*   cursor  = row_off + N;                        // N
    int*   csr_src = cursor + N;                         // E
    int*   pos     = csr_src + E;                        // E
    int*   bsums   = pos + E;                            // <=256

    float* heads      = out + NF;
    float* e1_out     = out + 2 * NF;
    float* atten0_out = e1_out + (size_t)E * 4;
    float* atten1_out = atten0_out + E;

    // ---- CSR build (int atomics only) ----
    hipMemsetAsync(deg, 0, (size_t)N * sizeof(int), stream);
    count_deg<<<(E + 255) / 256, 256, 0, stream>>>(dsts, deg, E);
    int nb = (N + 1023) / 1024;
    scan_block<<<nb, 256, 0, stream>>>(deg, row_off, bsums, N);
    scan_sums<<<1, 256, 0, stream>>>(bsums, nb);
    scan_finalize<<<(N + 255) / 256, 256, 0, stream>>>(row_off, bsums, cursor, N);
    fill_csr<<<(E + 255) / 256, 256, 0, stream>>>(dsts, srcs, cursor, csr_src, pos, E);

    const int gemm_blocks = (N + 63) / 64;
    const int agg_blocks  = (N + 3) / 4;

    // ---- layer 0 ----
    gemm128<<<gemm_blocks, 256, 0, stream>>>(x, W0, feat, N, 256);
    eler_kernel<<<(N * 4 + 255) / 256, 256, 0, stream>>>(feat, al0, ar0, el, er, N);
    edge_kernel<<<(E + 255) / 256, 256, 0, stream>>>(srcs, dsts, pos, el, er, exw,
                                                     nullptr, atten0_out, E);
    aggregate<0><<<agg_blocks, 256, 0, stream>>>(row_off, deg, csr_src, exw, feat,
                                                 nullptr, h1, nullptr, N);

    // ---- layer 1 ----
    gemm128<<<gemm_blocks, 256, 0, stream>>>(h1, W1, feat, N, 128);
    eler_kernel<<<(N * 4 + 255) / 256, 256, 0, stream>>>(feat, al1, ar1, el, er, N);
    edge_kernel<<<(E + 255) / 256, 256, 0, stream>>>(srcs, dsts, pos, el, er, exw,
                                                     e1_out, atten1_out, E);
    aggregate<1><<<agg_blocks, 256, 0, stream>>>(row_off, deg, csr_src, exw, feat,
                                                 h1, out, heads, N);
}